// Round 1
// baseline (508.052 us; speedup 1.0000x reference)
//
#include <hip/hip_runtime.h>
#include <cstdint>

#define ZFULL 136
#define NCTX 16
#define KDIM 152   // 136 + 16
#define KCLS 75
#define BM 32
#define BN 64

// ---------- build W_T[152][4096]: W_T[d][n] = K_params[n][d] (d<136) else label_mod[n][d-136] ----------
__global__ __launch_bounds__(256) void build_WT(const float* __restrict__ Kp,
                                                const float* __restrict__ Lm,
                                                float* __restrict__ WT) {
  int idx = blockIdx.x * 256 + threadIdx.x;
  if (idx >= KDIM * 4096) return;
  int n = idx & 4095;
  int d = idx >> 12;
  float v = (d < ZFULL) ? Kp[(size_t)n * ZFULL + d]
                        : Lm[(size_t)n * NCTX + (d - ZFULL)];
  WT[idx] = v;
}

// ---------- build A_T[152][CH]: A_T[d][m] = z_flat[b0+m][d] (d<136) else float(labels[b0+m][d-136]) ----------
__global__ __launch_bounds__(256) void build_AT(const float* __restrict__ z,
                                                const int* __restrict__ labels,
                                                float* __restrict__ AT,
                                                int b0, int CH) {
  int idx = blockIdx.x * 256 + threadIdx.x;
  if (idx >= KDIM * CH) return;
  int m = idx % CH;
  int d = idx / CH;
  int b = b0 + m;
  float v = (d < ZFULL) ? z[(size_t)b * ZFULL + d]
                        : (float)labels[(size_t)b * NCTX + (d - ZFULL)];
  AT[idx] = v;
}

// ---------- GEMM: rates[m][i*64+j] = exp(clip(base[i][j] + dot, -15, 3)), diag zeroed ----------
// tile: BM=32 batches x BN=64 (= all j of one i-row, i = blockIdx.y)
__global__ __launch_bounds__(256) void gemm_rates(const float* __restrict__ AT,
                                                  const float* __restrict__ WT,
                                                  const float* __restrict__ base_log,
                                                  float* __restrict__ rates,
                                                  int CH) {
  __shared__ float Ash[KDIM][BM];
  __shared__ float Wsh[KDIM][BN];
  const int tid = threadIdx.x;
  const int bm0 = blockIdx.x * BM;
  const int irow = blockIdx.y;       // 0..63
  const int n0 = irow * 64;

  for (int idx = tid; idx < KDIM * (BM / 4); idx += 256) {
    int d = idx >> 3;   // BM/4 == 8
    int c = idx & 7;
    *(float4*)&Ash[d][c * 4] = *(const float4*)&AT[(size_t)d * CH + bm0 + c * 4];
  }
  for (int idx = tid; idx < KDIM * (BN / 4); idx += 256) {
    int d = idx >> 4;   // BN/4 == 16
    int c = idx & 15;
    *(float4*)&Wsh[d][c * 4] = *(const float4*)&WT[(size_t)d * 4096 + n0 + c * 4];
  }
  __syncthreads();

  const int tx = tid & 15;   // 16 cols-groups of 4
  const int ty = tid >> 4;   // 16 row-groups of 2
  float acc[2][4] = {};
  #pragma unroll 4
  for (int k = 0; k < KDIM; ++k) {
    float2 av = *(const float2*)&Ash[k][ty * 2];
    float4 bv = *(const float4*)&Wsh[k][tx * 4];
    float ar[2] = {av.x, av.y};
    float br[4] = {bv.x, bv.y, bv.z, bv.w};
    #pragma unroll
    for (int r = 0; r < 2; ++r)
      #pragma unroll
      for (int c = 0; c < 4; ++c)
        acc[r][c] = fmaf(ar[r], br[c], acc[r][c]);
  }

  float4 bl = *(const float4*)&base_log[n0 + tx * 4];
  float blr[4] = {bl.x, bl.y, bl.z, bl.w};
  #pragma unroll
  for (int r = 0; r < 2; ++r) {
    int m = bm0 + ty * 2 + r;
    float ov[4];
    #pragma unroll
    for (int c = 0; c < 4; ++c) {
      int j = tx * 4 + c;
      float v = acc[r][c] + blr[c];
      v = fminf(fmaxf(v, -15.0f), 3.0f);
      float e = expf(v);
      ov[c] = (j == irow) ? 0.0f : e;
    }
    float4 o;
    o.x = ov[0]; o.y = ov[1]; o.z = ov[2]; o.w = ov[3];
    *(float4*)&rates[(size_t)m * 4096 + n0 + tx * 4] = o;
  }
}

// ---------- solve + attention + logits: one wave per batch, lane = column ----------
__global__ __launch_bounds__(256) void solve_kernel(const float* __restrict__ rates,
                                                    const int* __restrict__ labels,
                                                    const float* __restrict__ Bm,
                                                    float* __restrict__ out,
                                                    int b0) {
  __shared__ float Blds[64][16];
  __shared__ float xbuf[4][64];
  __shared__ float att_lds[4][16];
  __shared__ float acc[4][80];

  const int tid = threadIdx.x;
  for (int idx = tid; idx < 1024; idx += 256)
    Blds[idx >> 4][idx & 15] = Bm[idx];

  const int wave = tid >> 6;
  const int lane = tid & 63;
  const int batch = b0 + blockIdx.x * 4 + wave;
  const float* R = rates + (size_t)(blockIdx.x * 4 + wave) * 4096;

  // lane holds column `lane`: a[i] = K[i][lane]
  float a[64];
  #pragma unroll
  for (int i = 0; i < 64; ++i) a[i] = R[i * 64 + lane];

  float cs = 0.0f;                 // col_sum (diag entry is 0 from GEMM)
  #pragma unroll
  for (int i = 0; i < 64; ++i) cs += a[i];
  #pragma unroll
  for (int i = 0; i < 63; ++i) a[i] = (lane == i) ? -cs : a[i];
  a[63] = 1.0f;                    // normalization row

  // Gaussian elimination, no pivoting (leading block is column-diag-dominant).
  // b = e_63 stays e_63 through elimination (b[k]=0 for every pivot step).
  #pragma unroll
  for (int k = 0; k < 63; ++k) {
    float piv = __shfl(a[k], k);
    float rpiv = 1.0f / piv;
    #pragma unroll
    for (int i = k + 1; i < 64; ++i) {
      float m = __shfl(a[i], k) * rpiv;
      a[i] = fmaf(-m, a[k], a[i]);
    }
  }

  // back-substitution; lane j accumulates x[j]
  float x = 0.0f;
  #pragma unroll
  for (int k = 63; k >= 0; --k) {
    float t = a[k] * x;            // zero for lanes not yet solved / below-diag
    t += __shfl_xor(t, 32); t += __shfl_xor(t, 16); t += __shfl_xor(t, 8);
    t += __shfl_xor(t, 4);  t += __shfl_xor(t, 2);  t += __shfl_xor(t, 1);
    float bk = (k == 63) ? 1.0f : 0.0f;
    float xn = (bk - t) / a[k];    // only lane k's value is kept
    if (lane == k) x = xn;
  }

  // clip >= 0 and normalize
  x = fmaxf(x, 0.0f);
  float s = x;
  s += __shfl_xor(s, 32); s += __shfl_xor(s, 16); s += __shfl_xor(s, 8);
  s += __shfl_xor(s, 4);  s += __shfl_xor(s, 2);  s += __shfl_xor(s, 1);
  x = x / s;

  xbuf[wave][lane] = x;
  acc[wave][lane] = 1e-10f;
  if (lane < 16) acc[wave][64 + lane] = 1e-10f;
  __syncthreads();

  // q[t] = p . B[:,t] for t = lane < 16
  float q = 0.0f;
  if (lane < 16) {
    #pragma unroll 8
    for (int n = 0; n < 64; ++n) q = fmaf(xbuf[wave][n], Blds[n][lane], q);
  }
  // softmax over the 16 context lanes (masks <=8 keep exchange within the group)
  float qm = q;
  qm = fmaxf(qm, __shfl_xor(qm, 8)); qm = fmaxf(qm, __shfl_xor(qm, 4));
  qm = fmaxf(qm, __shfl_xor(qm, 2)); qm = fmaxf(qm, __shfl_xor(qm, 1));
  float e = expf(q - qm);
  float es = e;
  es += __shfl_xor(es, 8); es += __shfl_xor(es, 4);
  es += __shfl_xor(es, 2); es += __shfl_xor(es, 1);
  if (lane < 16) att_lds[wave][lane] = e / es;
  __syncthreads();

  // deterministic serial bucket-accumulate (no atomics)
  if (lane == 0) {
    #pragma unroll
    for (int n = 0; n < 16; ++n) {
      int lb = labels[(size_t)batch * 16 + n];
      acc[wave][lb - 1] += att_lds[wave][n];
    }
  }
  __syncthreads();

  float* ob = out + (size_t)batch * 75;
  ob[lane] = logf(acc[wave][lane]);          // 0..63  (63 < 75, valid)
  if (lane < 11) ob[64 + lane] = logf(acc[wave][64 + lane]);
}

extern "C" void kernel_launch(void* const* d_in, const int* in_sizes, int n_in,
                              void* d_out, int out_size, void* d_ws, size_t ws_size,
                              hipStream_t stream) {
  const float* z      = (const float*)d_in[0];
  const int*   labels = (const int*)d_in[1];
  const float* Kp     = (const float*)d_in[2];
  const float* Lm     = (const float*)d_in[3];
  const float* Bm     = (const float*)d_in[4];
  const float* base   = (const float*)d_in[5];
  float* out = (float*)d_out;

  const int bsz = in_sizes[0] / ZFULL;   // 8192

  float* WT = (float*)d_ws;
  const size_t WT_elems = (size_t)KDIM * 4096;

  // choose batch chunk CH so ws holds WT + AT(152xCH) + rates(CHx4096)
  int CH = bsz;
  while (CH > 64) {
    size_t need = (WT_elems + (size_t)KDIM * CH + (size_t)CH * 4096) * sizeof(float);
    if (need <= ws_size) break;
    CH >>= 1;
  }
  float* AT    = WT + WT_elems;
  float* rates = AT + (size_t)KDIM * CH;

  build_WT<<<(KDIM * 4096 + 255) / 256, 256, 0, stream>>>(Kp, Lm, WT);

  for (int b0 = 0; b0 < bsz; b0 += CH) {
    build_AT<<<(KDIM * CH + 255) / 256, 256, 0, stream>>>(z, labels, AT, b0, CH);
    dim3 g(CH / BM, 64);
    gemm_rates<<<g, 256, 0, stream>>>(AT, WT, base, rates, CH);
    solve_kernel<<<CH / 4, 256, 0, stream>>>(rates, labels, Bm, out, b0);
  }
}

// Round 2
// 283.897 us; speedup vs baseline: 1.7896x; 1.7896x over previous
//
#include <hip/hip_runtime.h>
#include <cstdint>

#define ZFULL 136
#define NCTX 16
#define KCLS 75

typedef __bf16 bf16x8 __attribute__((ext_vector_type(8)));
typedef float f32x4 __attribute__((ext_vector_type(4)));

__device__ __forceinline__ ushort bf16_rne(float v) {
  uint32_t u = __float_as_uint(v);
  return (ushort)((u + 0x7fffu + ((u >> 16) & 1u)) >> 16);
}

// ---- pack A: [CH/16 m_tiles][5 k_tiles][2 h][64 lane][8 j] ushorts (bf16) ----
__global__ __launch_bounds__(256) void pack_A(const float* __restrict__ z,
                                              const int* __restrict__ labels,
                                              ushort* __restrict__ Apk,
                                              int b0, int CH) {
  int idx = blockIdx.x * 256 + threadIdx.x;  // (mt,kt,h,lane)
  int lane = idx & 63;
  int h = (idx >> 6) & 1;
  int kt = (idx >> 7) % 5;
  int mt = idx / 640;
  if (mt >= CH / 16) return;
  int m = b0 + mt * 16 + (lane & 15);
  int kbase = kt * 32 + (lane >> 4) * 8;
  ushort o[8];
#pragma unroll
  for (int j = 0; j < 8; ++j) {
    int k = kbase + j;
    float v = 0.0f;
    if (k < ZFULL) v = z[(size_t)m * ZFULL + k];
    else if (k < ZFULL + NCTX) v = (float)labels[(size_t)m * NCTX + (k - ZFULL)];
    ushort hi = bf16_rne(v);
    if (h == 0) o[j] = hi;
    else {
      float fhi = __uint_as_float((uint32_t)hi << 16);
      o[j] = bf16_rne(v - fhi);
    }
  }
  uint4 w;
  w.x = (uint32_t)o[0] | ((uint32_t)o[1] << 16);
  w.y = (uint32_t)o[2] | ((uint32_t)o[3] << 16);
  w.z = (uint32_t)o[4] | ((uint32_t)o[5] << 16);
  w.w = (uint32_t)o[6] | ((uint32_t)o[7] << 16);
  *(uint4*)(Apk + (size_t)idx * 8) = w;
}

// ---- pack B: [256 n_tiles][5 k_tiles][2 h][64 lane][8 j] ushorts (bf16) ----
__global__ __launch_bounds__(256) void pack_B(const float* __restrict__ Kp,
                                              const float* __restrict__ Lm,
                                              ushort* __restrict__ Bpk) {
  int idx = blockIdx.x * 256 + threadIdx.x;
  int lane = idx & 63;
  int h = (idx >> 6) & 1;
  int kt = (idx >> 7) % 5;
  int nt = idx / 640;
  if (nt >= 256) return;
  int n = nt * 16 + (lane & 15);
  int kbase = kt * 32 + (lane >> 4) * 8;
  ushort o[8];
#pragma unroll
  for (int j = 0; j < 8; ++j) {
    int k = kbase + j;
    float v = 0.0f;
    if (k < ZFULL) v = Kp[(size_t)n * ZFULL + k];
    else if (k < ZFULL + NCTX) v = Lm[(size_t)n * NCTX + (k - ZFULL)];
    ushort hi = bf16_rne(v);
    if (h == 0) o[j] = hi;
    else {
      float fhi = __uint_as_float((uint32_t)hi << 16);
      o[j] = bf16_rne(v - fhi);
    }
  }
  uint4 w;
  w.x = (uint32_t)o[0] | ((uint32_t)o[1] << 16);
  w.y = (uint32_t)o[2] | ((uint32_t)o[3] << 16);
  w.z = (uint32_t)o[4] | ((uint32_t)o[5] << 16);
  w.w = (uint32_t)o[6] | ((uint32_t)o[7] << 16);
  *(uint4*)(Bpk + (size_t)idx * 8) = w;
}

// ---- split-bf16 MFMA GEMM, 128x128 block tile, no LDS (L2-resident packed operands) ----
__global__ __launch_bounds__(256) void gemm_mfma(const ushort* __restrict__ Apk,
                                                 const ushort* __restrict__ Bpk,
                                                 const float* __restrict__ base_log,
                                                 float* __restrict__ rates) {
  const int tid = threadIdx.x;
  const int lane = tid & 63;
  const int w = tid >> 6;
  const int wm = w & 1, wn = w >> 1;
  const int m_tile0 = blockIdx.x * 8 + wm * 4;
  const int n_tile0 = blockIdx.y * 8 + wn * 4;

  f32x4 acc[4][4] = {};

#pragma unroll
  for (int kt = 0; kt < 5; ++kt) {
    bf16x8 ah[4], al[4], bh[4], bl[4];
#pragma unroll
    for (int mt = 0; mt < 4; ++mt) {
      size_t off = (((size_t)(m_tile0 + mt) * 5 + kt) * 128 + lane) * 8;
      ah[mt] = *(const bf16x8*)(Apk + off);
      al[mt] = *(const bf16x8*)(Apk + off + 512);
    }
#pragma unroll
    for (int nt = 0; nt < 4; ++nt) {
      size_t off = (((size_t)(n_tile0 + nt) * 5 + kt) * 128 + lane) * 8;
      bh[nt] = *(const bf16x8*)(Bpk + off);
      bl[nt] = *(const bf16x8*)(Bpk + off + 512);
    }
#pragma unroll
    for (int mt = 0; mt < 4; ++mt)
#pragma unroll
      for (int nt = 0; nt < 4; ++nt) {
        acc[mt][nt] = __builtin_amdgcn_mfma_f32_16x16x32_bf16(ah[mt], bh[nt], acc[mt][nt], 0, 0, 0);
        acc[mt][nt] = __builtin_amdgcn_mfma_f32_16x16x32_bf16(ah[mt], bl[nt], acc[mt][nt], 0, 0, 0);
        acc[mt][nt] = __builtin_amdgcn_mfma_f32_16x16x32_bf16(al[mt], bh[nt], acc[mt][nt], 0, 0, 0);
      }
  }

  const int col_l = lane & 15;
  const int row_l = (lane >> 4) * 4;
#pragma unroll
  for (int mt = 0; mt < 4; ++mt) {
#pragma unroll
    for (int nt = 0; nt < 4; ++nt) {
      int n = (n_tile0 + nt) * 16 + col_l;
      int i = n >> 6, j = n & 63;
      float bse = base_log[n];
#pragma unroll
      for (int r = 0; r < 4; ++r) {
        int m = (m_tile0 + mt) * 16 + row_l + r;
        float v = acc[mt][nt][r] + bse;
        v = fminf(fmaxf(v, -15.0f), 3.0f);
        float e = (i == j) ? 0.0f : expf(v);
        rates[(size_t)m * 4096 + n] = e;
      }
    }
  }
}

// ---- solve + attention + logits: one wave per batch, lane = column ----
__global__ __launch_bounds__(256) void solve_kernel(const float* __restrict__ rates,
                                                    const int* __restrict__ labels,
                                                    const float* __restrict__ Bm,
                                                    float* __restrict__ out,
                                                    int b0) {
  __shared__ float Blds[64][16];
  __shared__ float xbuf[4][64];
  __shared__ float att_lds[4][16];
  __shared__ float acc[4][80];

  const int tid = threadIdx.x;
  for (int idx = tid; idx < 1024; idx += 256)
    Blds[idx >> 4][idx & 15] = Bm[idx];

  const int wave = tid >> 6;
  const int lane = tid & 63;
  const int batch = b0 + blockIdx.x * 4 + wave;
  const float* R = rates + (size_t)(blockIdx.x * 4 + wave) * 4096;

  // lane holds column `lane`: a[i] = K[i][lane]
  float a[64];
#pragma unroll
  for (int i = 0; i < 64; ++i) a[i] = R[i * 64 + lane];

  float cs = 0.0f;  // col_sum (diag entry is 0 from GEMM)
#pragma unroll
  for (int i = 0; i < 64; ++i) cs += a[i];
#pragma unroll
  for (int i = 0; i < 63; ++i) a[i] = (lane == i) ? -cs : a[i];
  a[63] = 1.0f;  // normalization row

  // Gaussian elimination with pivot-row pre-scaling (unit-diagonal U).
  // No pivoting: leading block is column-diagonally-dominant.
  // b = e_63 is untouched (b[k]=0 for every pivot row k<63).
#pragma unroll
  for (int k = 0; k < 63; ++k) {
    float piv = __shfl(a[k], k);
    float rp = __builtin_amdgcn_rcpf(piv);
    a[k] *= rp;  // pivot row now has 1 at column k
#pragma unroll
    for (int i = k + 1; i < 64; ++i) {
      float c = __shfl(a[i], k);
      a[i] = fmaf(-c, a[k], a[i]);
    }
  }

  // back-substitution (U has unit diagonal on rows 0..62); lane j holds x[j]
  float x = 0.0f;
  {
    float d = __shfl(a[63], 63);
    float x63 = 1.0f / d;
    if (lane == 63) x = x63;
  }
#pragma unroll
  for (int k = 62; k >= 0; --k) {
    float t = a[k] * x;  // nonzero only at solved lanes j>k
    t += __shfl_xor(t, 32); t += __shfl_xor(t, 16); t += __shfl_xor(t, 8);
    t += __shfl_xor(t, 4);  t += __shfl_xor(t, 2);  t += __shfl_xor(t, 1);
    if (lane == k) x = -t;  // b[k]=0, unit diag
  }

  // clip >= 0 and normalize
  x = fmaxf(x, 0.0f);
  float s = x;
  s += __shfl_xor(s, 32); s += __shfl_xor(s, 16); s += __shfl_xor(s, 8);
  s += __shfl_xor(s, 4);  s += __shfl_xor(s, 2);  s += __shfl_xor(s, 1);
  x = x / s;

  xbuf[wave][lane] = x;
  acc[wave][lane] = 1e-10f;
  if (lane < 16) acc[wave][64 + lane] = 1e-10f;
  __syncthreads();

  // q[t] = p . B[:,t] for t = lane < 16
  float q = 0.0f;
  if (lane < 16) {
#pragma unroll 8
    for (int n = 0; n < 64; ++n) q = fmaf(xbuf[wave][n], Blds[n][lane], q);
  }
  float qm = q;
  qm = fmaxf(qm, __shfl_xor(qm, 8)); qm = fmaxf(qm, __shfl_xor(qm, 4));
  qm = fmaxf(qm, __shfl_xor(qm, 2)); qm = fmaxf(qm, __shfl_xor(qm, 1));
  float e = expf(q - qm);
  float es = e;
  es += __shfl_xor(es, 8); es += __shfl_xor(es, 4);
  es += __shfl_xor(es, 2); es += __shfl_xor(es, 1);
  if (lane < 16) att_lds[wave][lane] = e / es;
  __syncthreads();

  // deterministic serial bucket-accumulate (no atomics)
  if (lane == 0) {
#pragma unroll
    for (int n = 0; n < 16; ++n) {
      int lb = labels[(size_t)batch * 16 + n];
      acc[wave][lb - 1] += att_lds[wave][n];
    }
  }
  __syncthreads();

  float* ob = out + (size_t)batch * 75;
  ob[lane] = logf(acc[wave][lane]);
  if (lane < 11) ob[64 + lane] = logf(acc[wave][64 + lane]);
}

extern "C" void kernel_launch(void* const* d_in, const int* in_sizes, int n_in,
                              void* d_out, int out_size, void* d_ws, size_t ws_size,
                              hipStream_t stream) {
  const float* z      = (const float*)d_in[0];
  const int*   labels = (const int*)d_in[1];
  const float* Kp     = (const float*)d_in[2];
  const float* Lm     = (const float*)d_in[3];
  const float* Bm     = (const float*)d_in[4];
  const float* base   = (const float*)d_in[5];
  float* out = (float*)d_out;

  const int bsz = in_sizes[0] / ZFULL;  // 8192

  const size_t B_bytes = (size_t)256 * 5 * 2 * 64 * 8 * sizeof(ushort);  // 2.62 MB
  int CH = bsz;
  while (CH > 128) {
    size_t A_bytes = (size_t)(CH / 16) * 5 * 2 * 64 * 8 * sizeof(ushort);
    size_t need = B_bytes + A_bytes + (size_t)CH * 4096 * sizeof(float);
    if (need <= ws_size) break;
    CH >>= 1;
  }
  ushort* Bpk = (ushort*)d_ws;
  ushort* Apk = (ushort*)((char*)d_ws + B_bytes);
  size_t A_bytes = (size_t)(CH / 16) * 5 * 2 * 64 * 8 * sizeof(ushort);
  float* rates = (float*)((char*)d_ws + B_bytes + A_bytes);

  pack_B<<<(256 * 640 + 255) / 256, 256, 0, stream>>>(Kp, Lm, Bpk);

  for (int b0 = 0; b0 < bsz; b0 += CH) {
    int a_threads = (CH / 16) * 640;
    pack_A<<<(a_threads + 255) / 256, 256, 0, stream>>>(z, labels, Apk, b0, CH);
    dim3 g(CH / 128, 32);
    gemm_mfma<<<g, 256, 0, stream>>>(Apk, Bpk, base, rates);
    solve_kernel<<<CH / 4, 256, 0, stream>>>(rates, labels, Bm, out, b0);
  }
}